// Round 2
// baseline (31.551 us; speedup 1.0000x reference)
//
#include <hip/hip_runtime.h>

#define BATCH 262144
#define NUM_LAYERS 64

// One thread per batch element. Complex 2-amplitude state lives in registers;
// sequential loop over 64 layers.
// MODE 0: output is float32 REAL PART only, layout (L, B, 2) -> float2 per (l,b).
// MODE 1: output is complex64 viewed as float32, layout (L, B, 2, re/im)
//         -> float4 per (l,b).
template <int MODE>
__global__ __launch_bounds__(256) void squbit_kernel(
    const float* __restrict__ X,       // (BATCH, 2)
    const float* __restrict__ W,       // (NUM_LAYERS, 3)
    const float* __restrict__ Bi,      // (NUM_LAYERS, 3)
    float* __restrict__ out)
{
    // Per-layer derived constants, computed once per block into LDS.
    __shared__ float4 c4[NUM_LAYERS];  // {0.5*w0, 0.5*b0, 0.5*w1, 0.5*b1}
    __shared__ float  com[NUM_LAYERS]; // 0.5*(w2 + b2)

    const int t = threadIdx.x;
    if (t < NUM_LAYERS) {
        const float w0 = W[t * 3 + 0], w1 = W[t * 3 + 1], w2 = W[t * 3 + 2];
        const float b0 = Bi[t * 3 + 0], b1 = Bi[t * 3 + 1], b2 = Bi[t * 3 + 2];
        c4[t]  = make_float4(0.5f * w0, 0.5f * b0, 0.5f * w1, 0.5f * b1);
        com[t] = 0.5f * (w2 + b2);
    }
    __syncthreads();

    const int b = blockIdx.x * 256 + t;
    const float2 x = *reinterpret_cast<const float2*>(X + 2 * b);

    // state s = (1, 0)
    float s0r = 1.0f, s0i = 0.0f, s1r = 0.0f, s1i = 0.0f;

    float2* o2 = reinterpret_cast<float2*>(out) + b;
    float4* o4 = reinterpret_cast<float4*>(out) + b;

    #pragma unroll 4
    for (int l = 0; l < NUM_LAYERS; ++l) {
        const float4 c  = c4[l];
        const float omh = com[l];

        // half-angles
        const float ph  = fmaf(x.x, c.x, c.y);   // 0.5 * phi
        const float th  = fmaf(x.y, c.z, c.w);   // 0.5 * theta
        const float ppo = ph + omh;              // (phi+omega)/2
        const float pmo = ph - omh;              // (phi-omega)/2

        float st, ct, sp, cp, sm, cm;
        __sincosf(th,  &st, &ct);
        __sincosf(ppo, &sp, &cp);
        __sincosf(pmo, &sm, &cm);

        // m00 = ( ct*cp, -ct*sp)   m01 = (-st*cm, -st*sm)
        // m10 = ( st*cm, -st*sm)   m11 = ( ct*cp,  ct*sp)
        const float m00r =  ct * cp, m00i = -ct * sp;
        const float m01r = -st * cm, m01i = -st * sm;
        const float m10r =  st * cm, m10i = -st * sm;
        const float m11r =  ct * cp, m11i =  ct * sp;

        // s' = M * s (complex 2x2 matvec)
        const float n0r = m00r * s0r - m00i * s0i + m01r * s1r - m01i * s1i;
        const float n0i = m00r * s0i + m00i * s0r + m01r * s1i + m01i * s1r;
        const float n1r = m10r * s0r - m10i * s0i + m11r * s1r - m11i * s1i;
        const float n1i = m10r * s0i + m10i * s0r + m11r * s1i + m11i * s1r;

        s0r = n0r; s0i = n0i; s1r = n1r; s1i = n1i;

        if (MODE == 0) {
            o2[l * BATCH] = make_float2(s0r, s1r);
        } else {
            o4[l * BATCH] = make_float4(s0r, s0i, s1r, s1i);
        }
    }
}

extern "C" void kernel_launch(void* const* d_in, const int* in_sizes, int n_in,
                              void* d_out, int out_size, void* d_ws, size_t ws_size,
                              hipStream_t stream) {
    const float* X  = (const float*)d_in[0];
    const float* W  = (const float*)d_in[1];
    const float* Bi = (const float*)d_in[2];
    float* out = (float*)d_out;

    dim3 grid(BATCH / 256), block(256);

    const long long full_complex_floats = (long long)NUM_LAYERS * BATCH * 4;
    if ((long long)out_size >= full_complex_floats) {
        // Buffer holds interleaved re/im (complex64 viewed as float32).
        squbit_kernel<1><<<grid, block, 0, stream>>>(X, W, Bi, out);
    } else {
        // Buffer holds real part only: (L, B, 2) float32.
        squbit_kernel<0><<<grid, block, 0, stream>>>(X, W, Bi, out);
    }
}

// Round 3
// 29.041 us; speedup vs baseline: 1.0864x; 1.0864x over previous
//
#include <hip/hip_runtime.h>

#define BATCH 262144
#define NUM_LAYERS 64

// U(phi,theta,omega) = Rz(omega) * Ry(theta) * Rz(phi)  (matches reference M).
// We propagate u_l = Rz(-omega_l) * t_l  (the pre-omega state):
//   u_l = Ry(theta_l) * Rz(phi_l + omega_{l-1}) * u_{l-1}
// and the true state (needed only for the store) is t_l = Rz(omega_l) * u_l.
// omega is batch-independent, so sincos(omega/2) is precomputed per layer, and
// phi_l + omega_{l-1} still needs only ONE fma (bias adjusted per layer).
// Each thread handles TWO batch elements -> one float4 store per layer.
//
// MODE 0: out holds float32 REAL parts, layout (L, B, 2)  -> float4 per (l, 2 elems)
// MODE 1: out holds complex64 viewed as float32 (L, B, 2) -> 2x float4 per (l, 2 elems)
template <int MODE>
__global__ __launch_bounds__(256) void squbit_kernel(
    const float* __restrict__ X,       // (BATCH, 2)
    const float* __restrict__ W,       // (NUM_LAYERS, 3)
    const float* __restrict__ Bi,      // (NUM_LAYERS, 3)
    float* __restrict__ out)
{
    __shared__ float4 cA[NUM_LAYERS];   // {0.5*w0, 0.5*b0 + hom_prev, 0.5*w1, 0.5*b1}
    __shared__ float2 cOm[NUM_LAYERS];  // {cos(om/2), sin(om/2)}

    const int t = threadIdx.x;
    if (t < NUM_LAYERS) {
        const float w0 = W[t * 3 + 0], w1 = W[t * 3 + 1], w2 = W[t * 3 + 2];
        const float b0 = Bi[t * 3 + 0], b1 = Bi[t * 3 + 1], b2 = Bi[t * 3 + 2];
        float hom_prev = 0.0f;
        if (t > 0) hom_prev = 0.5f * (W[(t - 1) * 3 + 2] + Bi[(t - 1) * 3 + 2]);
        cA[t] = make_float4(0.5f * w0, fmaf(0.5f, b0, hom_prev), 0.5f * w1, 0.5f * b1);
        const float hom = 0.5f * (w2 + b2);
        float so, co;
        __sincosf(hom, &so, &co);
        cOm[t] = make_float2(co, so);
    }
    __syncthreads();

    const int g = blockIdx.x * 256 + t;          // handles batch elems 2g, 2g+1
    const float4 xx = reinterpret_cast<const float4*>(X)[g];

    // pre-omega states u = (u0, u1), init (1,0)
    float Aur0 = 1.0f, Aui0 = 0.0f, Aur1 = 0.0f, Aui1 = 0.0f;
    float Bur0 = 1.0f, Bui0 = 0.0f, Bur1 = 0.0f, Bui1 = 0.0f;

    float4* o4 = reinterpret_cast<float4*>(out);

    #pragma unroll 4
    for (int l = 0; l < NUM_LAYERS; ++l) {
        const float4 c = cA[l];
        const float2 om = cOm[l];

        // ---- element A ----
        {
            const float hpsi = fmaf(xx.x, c.x, c.y);
            const float hth  = fmaf(xx.y, c.z, c.w);
            float sps, cps, sth, cth;
            __sincosf(hpsi, &sps, &cps);
            __sincosf(hth,  &sth, &cth);
            // Rz(psi): a0 = u0*(c - i s); a1 = u1*(c + i s)
            const float a0r = fmaf(Aui0,  sps, Aur0 * cps);
            const float a0i = fmaf(Aur0, -sps, Aui0 * cps);
            const float a1r = fmaf(Aui1, -sps, Aur1 * cps);
            const float a1i = fmaf(Aur1,  sps, Aui1 * cps);
            // Ry(th)
            Aur0 = fmaf(-sth, a1r, cth * a0r);
            Aui0 = fmaf(-sth, a1i, cth * a0i);
            Aur1 = fmaf( sth, a0r, cth * a1r);
            Aui1 = fmaf( sth, a0i, cth * a1i);
        }
        // ---- element B ----
        {
            const float hpsi = fmaf(xx.z, c.x, c.y);
            const float hth  = fmaf(xx.w, c.z, c.w);
            float sps, cps, sth, cth;
            __sincosf(hpsi, &sps, &cps);
            __sincosf(hth,  &sth, &cth);
            const float a0r = fmaf(Bui0,  sps, Bur0 * cps);
            const float a0i = fmaf(Bur0, -sps, Bui0 * cps);
            const float a1r = fmaf(Bui1, -sps, Bur1 * cps);
            const float a1i = fmaf(Bur1,  sps, Bui1 * cps);
            Bur0 = fmaf(-sth, a1r, cth * a0r);
            Bui0 = fmaf(-sth, a1i, cth * a0i);
            Bur1 = fmaf( sth, a0r, cth * a1r);
            Bui1 = fmaf( sth, a0i, cth * a1i);
        }

        // store-side Rz(omega): t0 = u0*(co - i so), t1 = u1*(co + i so)
        if (MODE == 0) {
            const float At0r = fmaf(Aui0,  om.y, Aur0 * om.x);
            const float At1r = fmaf(Aui1, -om.y, Aur1 * om.x);
            const float Bt0r = fmaf(Bui0,  om.y, Bur0 * om.x);
            const float Bt1r = fmaf(Bui1, -om.y, Bur1 * om.x);
            o4[l * (BATCH / 2) + g] = make_float4(At0r, At1r, Bt0r, Bt1r);
        } else {
            const float At0r = fmaf(Aui0,  om.y, Aur0 * om.x);
            const float At0i = fmaf(Aur0, -om.y, Aui0 * om.x);
            const float At1r = fmaf(Aui1, -om.y, Aur1 * om.x);
            const float At1i = fmaf(Aur1,  om.y, Aui1 * om.x);
            const float Bt0r = fmaf(Bui0,  om.y, Bur0 * om.x);
            const float Bt0i = fmaf(Bur0, -om.y, Bui0 * om.x);
            const float Bt1r = fmaf(Bui1, -om.y, Bur1 * om.x);
            const float Bt1i = fmaf(Bur1,  om.y, Bui1 * om.x);
            o4[(l * BATCH + 2 * g) + 0] = make_float4(At0r, At0i, At1r, At1i);
            o4[(l * BATCH + 2 * g) + 1] = make_float4(Bt0r, Bt0i, Bt1r, Bt1i);
        }
    }
}

extern "C" void kernel_launch(void* const* d_in, const int* in_sizes, int n_in,
                              void* d_out, int out_size, void* d_ws, size_t ws_size,
                              hipStream_t stream) {
    const float* X  = (const float*)d_in[0];
    const float* W  = (const float*)d_in[1];
    const float* Bi = (const float*)d_in[2];
    float* out = (float*)d_out;

    dim3 grid(BATCH / 512), block(256);   // 2 batch elems per thread

    const long long full_complex_floats = (long long)NUM_LAYERS * BATCH * 4;
    if ((long long)out_size >= full_complex_floats) {
        squbit_kernel<1><<<grid, block, 0, stream>>>(X, W, Bi, out);
    } else {
        squbit_kernel<0><<<grid, block, 0, stream>>>(X, W, Bi, out);
    }
}